// Round 12
// baseline (304.965 us; speedup 1.0000x reference)
//
#include <hip/hip_runtime.h>
#include <hip/hip_bf16.h>

#define B_    64
#define L_    512
#define D_    768
#define NF_   100
#define W_    768
#define TOK_  3
#define CLS_  2
#define MTOT_ (B_ * L_)   // 32768
#define KP_   896         // padded K (768 seq + 128 padded enr)
#define NFP_  128         // padded NF
#define AST   904         // A LDS row stride (shorts), 16B-aligned, 2-way-free banks

typedef __attribute__((ext_vector_type(8))) short  bf16x8;
typedef __attribute__((ext_vector_type(4))) float  f32x4;

__device__ __forceinline__ unsigned short f2bf(float f) {
    union { float f; unsigned int u; } v; v.f = f;
    unsigned int u = v.u;
    u += 0x7fffu + ((u >> 16) & 1u);   // RNE
    return (unsigned short)(u >> 16);
}

__device__ __forceinline__ unsigned int pk2(float x, float y) {
    __hip_bfloat162 h = __float22bfloat162_rn(make_float2(x, y)); // v_cvt_pk_bf16_f32
    return *(unsigned int*)&h;
}

typedef __attribute__((address_space(3))) unsigned int        lds_uint;
typedef const __attribute__((address_space(1))) unsigned int  gbl_uint;

__device__ __forceinline__ void gload_lds16(const void* gp, void* lp) {
    __builtin_amdgcn_global_load_lds((gbl_uint*)gp, (lds_uint*)lp, 16, 0, 0);
}

// ======== setup: compact+cnt | cls | tag init | ewt | zrow | w1 transpose ======
__global__ void setup_kernel(const int* __restrict__ valid, int* __restrict__ gidx,
                             int* __restrict__ cnt,
                             const float* __restrict__ seq, const float* __restrict__ cls_w,
                             const float* __restrict__ cls_b, float* __restrict__ cls_out,
                             const float* __restrict__ b2, float* __restrict__ tag,
                             const float* __restrict__ enr_w, unsigned short* __restrict__ ewt,
                             float* __restrict__ zrow,
                             const float* __restrict__ w1, unsigned short* __restrict__ w1t) {
    const int bx = blockIdx.x, tid = threadIdx.x;
    if (bx < 64) {                       // ---- valid compaction + count ----
        __shared__ int s[L_];
        int v = valid[bx * L_ + tid];
        s[tid] = v;
        __syncthreads();
        for (int off = 1; off < L_; off <<= 1) {
            int x = (tid >= off) ? s[tid - off] : 0;
            __syncthreads();
            s[tid] += x;
            __syncthreads();
        }
        int inc = s[tid];
        if (tid == L_ - 1) cnt[bx] = inc;
        gidx[bx * L_ + tid] = -1;
        __syncthreads();
        if (v) gidx[bx * L_ + inc - 1] = tid;
    } else if (bx < 128) {               // ---- cls head ----
        const int b = bx - 64;
        __shared__ float r0[8], r1[8];
        const float* row = seq + (size_t)b * L_ * D_;
        float a0 = 0.f, a1 = 0.f;
        for (int d = tid; d < D_; d += 512) {
            float x = row[d];
            a0 += x * cls_w[d * CLS_ + 0];
            a1 += x * cls_w[d * CLS_ + 1];
        }
        for (int off = 32; off; off >>= 1) {
            a0 += __shfl_down(a0, off);
            a1 += __shfl_down(a1, off);
        }
        if ((tid & 63) == 0) { r0[tid >> 6] = a0; r1[tid >> 6] = a1; }
        __syncthreads();
        if (tid == 0) {
            float x0 = 0.f, x1 = 0.f;
            for (int i = 0; i < 8; ++i) { x0 += r0[i]; x1 += r1[i]; }
            cls_out[b * CLS_ + 0] = x0 + cls_b[0];
            cls_out[b * CLS_ + 1] = x1 + cls_b[1];
        }
    } else if (bx < 320) {               // ---- tag init to b2 ----
        int i = (bx - 128) * 512 + tid;  // < 98304 exactly
        tag[i] = b2[i % TOK_];
    } else if (bx < 352) {               // ---- ewt transpose+pad ----
        int j = (bx - 320) * 512 + tid;  // < 16384 exactly
        int n = j >> 7, k = j & 127;
        ewt[j] = (n < NF_ && k < NF_) ? f2bf(enr_w[k * NF_ + n]) : (unsigned short)0;
    } else if (bx < 354) {               // ---- zero row (unused, kept) ----
        int i = (bx - 352) * 512 + tid;
        if (i < D_) zrow[i] = 0.f;
    } else {                             // ---- w1t[n][k] = bf16(w1[k][n]) ----
        __shared__ unsigned short tile[64][80];
        const int p = bx - 354;          // 168 = 14 ktiles x 12 ntiles
        const int kb = p % 14, nb = p / 14;
        const int k0 = kb * 64, n0 = nb * 64;
        const int kr = tid >> 3, cq = tid & 7;
        const int k = k0 + kr;
        const bool ok = k < (D_ + NF_);
        const float* src = w1 + (size_t)k * W_ + n0 + cq * 8;
        float4 v0 = ok ? *(const float4*)src       : make_float4(0.f,0.f,0.f,0.f);
        float4 v1 = ok ? *(const float4*)(src + 4) : make_float4(0.f,0.f,0.f,0.f);
        int nl = cq * 8;
        tile[nl+0][kr] = f2bf(v0.x); tile[nl+1][kr] = f2bf(v0.y);
        tile[nl+2][kr] = f2bf(v0.z); tile[nl+3][kr] = f2bf(v0.w);
        tile[nl+4][kr] = f2bf(v1.x); tile[nl+5][kr] = f2bf(v1.y);
        tile[nl+6][kr] = f2bf(v1.z); tile[nl+7][kr] = f2bf(v1.w);
        __syncthreads();
        const int nr = tid >> 3, kq = tid & 7;
        uint4 a = *(const uint4*)&tile[nr][kq * 8];
        *(uint4*)(w1t + (size_t)(n0 + nr) * KP_ + k0 + kq * 8) = a;
    }
}

// ======== main: persistent-A in LDS + B double-buffer pipeline + fused enrich ==
// BM=64, BN=256, BK=32. 512 thr = 8 waves, wave tile 32m x 64n. A panel (64x896
// bf16) staged ONCE (HBM latency paid once, bandwidth-parallel); enrichment
// computed in-block into A's k>=768 slice; K-loop: 1 barrier/kt, B(kt+1) DMA
// fired before compute(kt) -> L2 latency covered by compute.
#define BM 64
#define BN 256

__global__ __launch_bounds__(512, 1)
void main_gemm(const float* __restrict__ seq, const int* __restrict__ gidx,
               const int* __restrict__ cnt, const float* __restrict__ feat,
               const unsigned short* __restrict__ ewt, const float* __restrict__ eb,
               const unsigned short* __restrict__ w1t,
               const float* __restrict__ b1, const float* __restrict__ w2,
               float* __restrict__ tag) {
    __shared__ unsigned short As[BM * AST];     // 115,712 B
    __shared__ unsigned short Bs[2][BN * 32];   // 2 x 16 KB
    __shared__ float tagbuf[BM * TOK_];         // 768 B   (total ~148.5 KB)

    const int tid  = threadIdx.x;
    const int lane = tid & 63;
    const int wv   = tid >> 6;          // 0..7
    const int fl   = lane & 15;
    const int fq   = lane >> 4;
    const int sw   = fq ^ (fl & 3);
    // XCD swizzle: 3 n-siblings of each m-tile on the same XCD residue
    const int g    = blockIdx.x;        // grid 1536 = 8 xcd * 192
    const int j    = g >> 3;
    const int nblk = j % 3;
    const int mblk = (j / 3) * 8 + (g & 7);
    const int row0 = mblk * BM;
    const int n0   = nblk * BN;

    if (tid < BM * TOK_) tagbuf[tid] = 0.f;

    const bool live = (row0 & (L_ - 1)) < cnt[row0 >> 9];
    const int kt0 = live ? 0 : 24;      // dead blocks: only enriched K-slice

    // ---- stage A panel: thread -> (row sm, k-segment s8) ----
    const int sm  = tid >> 3;
    const int s8  = tid & 7;
    const int row = row0 + sm;
    const int gi = gidx[row];
    if (live) {  // seq half: 96 floats -> bf16 (zeros for invalid rows)
        unsigned short* dst = &As[sm * AST + s8 * 96];
        if (gi >= 0) {
            const float* sr = seq + (((size_t)(row >> 9) << 9) + gi) * D_ + s8 * 96;
#pragma unroll
            for (int jj = 0; jj < 12; ++jj) {
                float4 v0 = *(const float4*)(sr + jj * 8);
                float4 v1 = *(const float4*)(sr + jj * 8 + 4);
                uint4 wo = { pk2(v0.x, v0.y), pk2(v0.z, v0.w),
                             pk2(v1.x, v1.y), pk2(v1.z, v1.w) };
                *(uint4*)(dst + jj * 8) = wo;
            }
        } else {
            const uint4 z = {0u, 0u, 0u, 0u};
#pragma unroll
            for (int jj = 0; jj < 12; ++jj) *(uint4*)(dst + jj * 8) = z;
        }
    }
    {   // feat: 16 k-slots per thread into k in [768, 896)
        unsigned short* dst = &As[sm * AST + D_ + s8 * 16];
        const float* fr = feat + (size_t)row * NF_;
#pragma unroll
        for (int jj = 0; jj < 4; ++jj) {
            int k = s8 * 16 + jj * 4;
            float4 v = (k + 4 <= NF_) ? *(const float4*)(fr + k)
                                      : make_float4(0.f, 0.f, 0.f, 0.f);
            uint2 wo = { pk2(v.x, v.y), pk2(v.z, v.w) };
            *(uint2*)(dst + jj * 4) = wo;
        }
    }
    __syncthreads();

    // ---- in-block enrichment: A_enr = relu(featA @ ewt + eb) (R10-proven) ----
    {
        f32x4 ec[4];
        const f32x4 zz = {0.f, 0.f, 0.f, 0.f};
        ec[0] = zz; ec[1] = zz; ec[2] = zz; ec[3] = zz;
#pragma unroll
        for (int kk = 0; kk < 4; ++kk) {
            bf16x8 bf = *(const bf16x8*)(ewt + (size_t)(wv * 16 + fl) * NFP_ + kk * 32 + fq * 8);
#pragma unroll
            for (int mt = 0; mt < 4; ++mt) {
                bf16x8 af = *(const bf16x8*)&As[(mt * 16 + fl) * AST + D_ + kk * 32 + fq * 8];
                ec[mt] = __builtin_amdgcn_mfma_f32_16x16x32_bf16(af, bf, ec[mt], 0, 0, 0);
            }
        }
        __syncthreads();   // all feat reads done before overwrite
        const int n = wv * 16 + fl;
        const float bias = (n < NF_) ? eb[n] : 0.f;
#pragma unroll
        for (int mt = 0; mt < 4; ++mt)
#pragma unroll
            for (int r = 0; r < 4; ++r) {
                float x = ec[mt][r] + bias;
                x = x > 0.f ? x : 0.f;
                As[(mt * 16 + fq * 4 + r) * AST + D_ + n] = f2bf(x);
            }
    }
    // ---- prologue: fire B(kt0) into buf (kt0&1)==0 ----
    const int bn = lane >> 2;
    const int bc = (lane & 3) ^ (bn & 3);
#pragma unroll
    for (int it = 0; it < 2; ++it) {
        int nr0 = wv * 32 + it * 16;
        gload_lds16(w1t + (size_t)(n0 + nr0 + bn) * KP_ + kt0 * 32 + bc * 8,
                    &Bs[0][nr0 * 32]);
    }
    __syncthreads();   // enr writes visible + B(kt0) drained

    // ---- K-loop: 1 barrier per kt; B prefetch distance 1 ----
    const int wvm = wv >> 2, wvn = wv & 3;   // 2 x 4 wave grid
    f32x4 acc[2][4];
    const f32x4 zz = {0.f, 0.f, 0.f, 0.f};
#pragma unroll
    for (int i = 0; i < 2; ++i)
#pragma unroll
        for (int jn = 0; jn < 4; ++jn) acc[i][jn] = zz;

#pragma unroll 2
    for (int kt = kt0; kt < 28; ++kt) {
        const int buf = kt & 1;
        if (kt + 1 < 28) {   // fire B(kt+1) into the other buffer
#pragma unroll
            for (int it = 0; it < 2; ++it) {
                int nr0 = wv * 32 + it * 16;
                gload_lds16(w1t + (size_t)(n0 + nr0 + bn) * KP_ + (kt + 1) * 32 + bc * 8,
                            &Bs[buf ^ 1][nr0 * 32]);
            }
        }
        // compute kt: A from resident panel, B from Bs[buf]; 8 MFMA/wave
        bf16x8 af[2], bfr[4];
#pragma unroll
        for (int mt = 0; mt < 2; ++mt)
            af[mt] = *(const bf16x8*)&As[(wvm * 32 + mt * 16 + fl) * AST + kt * 32 + fq * 8];
#pragma unroll
        for (int nt = 0; nt < 4; ++nt)
            bfr[nt] = *(const bf16x8*)&Bs[buf][(wvn * 64 + nt * 16 + fl) * 32 + sw * 8];
#pragma unroll
        for (int mt = 0; mt < 2; ++mt)
#pragma unroll
            for (int nt = 0; nt < 4; ++nt)
                acc[mt][nt] = __builtin_amdgcn_mfma_f32_16x16x32_bf16(af[mt], bfr[nt], acc[mt][nt], 0, 0, 0);
        __syncthreads();   // compute(kt) done + B(kt+1) DMA drained
    }

    // ---- epilogue: h = relu(acc+b1); tag partial = h@w2; reduce; atomics ----
    float b1v[4], w2v[4][TOK_];
#pragma unroll
    for (int nt = 0; nt < 4; ++nt) {
        int n = n0 + wvn * 64 + nt * 16 + fl;
        b1v[nt] = b1[n];
#pragma unroll
        for (int t = 0; t < TOK_; ++t) w2v[nt][t] = w2[n * TOK_ + t];
    }
#pragma unroll
    for (int mt = 0; mt < 2; ++mt)
#pragma unroll
        for (int r = 0; r < 4; ++r) {
            float s[TOK_] = {0.f, 0.f, 0.f};
#pragma unroll
            for (int nt = 0; nt < 4; ++nt) {
                float h = acc[mt][nt][r] + b1v[nt];
                h = h > 0.f ? h : 0.f;
#pragma unroll
                for (int t = 0; t < TOK_; ++t) s[t] += h * w2v[nt][t];
            }
#pragma unroll
            for (int off = 8; off; off >>= 1)
#pragma unroll
                for (int t = 0; t < TOK_; ++t) s[t] += __shfl_down(s[t], off, 16);
            if (fl == 0) {
                int m = wvm * 32 + mt * 16 + fq * 4 + r;
#pragma unroll
                for (int t = 0; t < TOK_; ++t) atomicAdd(&tagbuf[m * TOK_ + t], s[t]);
            }
        }
    __syncthreads();
    if (tid < BM * TOK_)
        atomicAdd(&tag[(size_t)row0 * TOK_ + tid], tagbuf[tid]);
}

extern "C" void kernel_launch(void* const* d_in, const int* in_sizes, int n_in,
                              void* d_out, int out_size, void* d_ws, size_t ws_size,
                              hipStream_t stream) {
    const float* seq   = (const float*)d_in[0];
    const float* feat  = (const float*)d_in[1];
    const int*   valid = (const int*)d_in[2];
    const float* enr_w = (const float*)d_in[3];
    const float* enr_b = (const float*)d_in[4];
    const float* w1    = (const float*)d_in[5];
    const float* b1    = (const float*)d_in[6];
    const float* w2    = (const float*)d_in[7];
    const float* b2    = (const float*)d_in[8];
    const float* cls_w = (const float*)d_in[9];
    const float* cls_b = (const float*)d_in[10];

    float* out = (float*)d_out;
    float* cls_out = out;                  // [64,2]
    float* tag_out = out + B_ * CLS_;      // [32768,3]

    // ws: w1t | ewt | gidx | zrow | cnt  (~1.6 MB)
    unsigned short* w1t  = (unsigned short*)d_ws;                 // 768*896*2 B
    unsigned short* ewt  = w1t + (size_t)W_ * KP_;                // 128*128*2 B
    int*            gidx = (int*)(ewt + (size_t)NFP_ * NFP_);     // 32768*4 B
    float*          zrow = (float*)(gidx + MTOT_);                // 768*4 B
    int*            cnt  = (int*)(zrow + D_);                     // 64*4 B

    setup_kernel<<<522, 512, 0, stream>>>(valid, gidx, cnt, seq, cls_w, cls_b, cls_out,
                                          b2, tag_out, enr_w, ewt, zrow, w1, w1t);
    main_gemm<<<(MTOT_ / BM) * 3, 512, 0, stream>>>(seq, gidx, cnt, feat, ewt, enr_b,
                                                    w1t, b1, w2, tag_out);
}

// Round 13
// 257.554 us; speedup vs baseline: 1.1841x; 1.1841x over previous
//
#include <hip/hip_runtime.h>
#include <hip/hip_bf16.h>

#define B_    64
#define L_    512
#define D_    768
#define NF_   100
#define W_    768
#define TOK_  3
#define CLS_  2
#define MTOT_ (B_ * L_)   // 32768
#define KP_   896         // padded K (768 seq + 128 padded enr)
#define NFP_  128         // padded NF

typedef __attribute__((ext_vector_type(8))) short  bf16x8;
typedef __attribute__((ext_vector_type(4))) float  f32x4;

__device__ __forceinline__ unsigned short f2bf(float f) {
    union { float f; unsigned int u; } v; v.f = f;
    unsigned int u = v.u;
    u += 0x7fffu + ((u >> 16) & 1u);   // RNE
    return (unsigned short)(u >> 16);
}

__device__ __forceinline__ unsigned int pk2(float x, float y) {
    __hip_bfloat162 h = __float22bfloat162_rn(make_float2(x, y)); // v_cvt_pk_bf16_f32
    return *(unsigned int*)&h;
}

typedef __attribute__((address_space(3))) unsigned int        lds_uint;
typedef const __attribute__((address_space(1))) unsigned int  gbl_uint;

__device__ __forceinline__ void gload_lds16(const void* gp, void* lp) {
    __builtin_amdgcn_global_load_lds((gbl_uint*)gp, (lds_uint*)lp, 16, 0, 0);
}

// ======== setup: compact+cnt | cls | tag init | ewt | w1 transpose =============
// grid 520 x 512thr
__global__ void setup_kernel(const int* __restrict__ valid, int* __restrict__ gidx,
                             int* __restrict__ cnt,
                             const float* __restrict__ seq, const float* __restrict__ cls_w,
                             const float* __restrict__ cls_b, float* __restrict__ cls_out,
                             const float* __restrict__ b2, float* __restrict__ tag,
                             const float* __restrict__ enr_w, unsigned short* __restrict__ ewt,
                             const float* __restrict__ w1, unsigned short* __restrict__ w1t) {
    const int bx = blockIdx.x, tid = threadIdx.x;
    if (bx < 64) {                       // ---- valid compaction + count ----
        __shared__ int s[L_];
        int v = valid[bx * L_ + tid];
        s[tid] = v;
        __syncthreads();
        for (int off = 1; off < L_; off <<= 1) {
            int x = (tid >= off) ? s[tid - off] : 0;
            __syncthreads();
            s[tid] += x;
            __syncthreads();
        }
        int inc = s[tid];
        if (tid == L_ - 1) cnt[bx] = inc;
        gidx[bx * L_ + tid] = -1;
        __syncthreads();
        if (v) gidx[bx * L_ + inc - 1] = tid;
    } else if (bx < 128) {               // ---- cls head ----
        const int b = bx - 64;
        __shared__ float r0[8], r1[8];
        const float* row = seq + (size_t)b * L_ * D_;
        float a0 = 0.f, a1 = 0.f;
        for (int d = tid; d < D_; d += 512) {
            float x = row[d];
            a0 += x * cls_w[d * CLS_ + 0];
            a1 += x * cls_w[d * CLS_ + 1];
        }
        for (int off = 32; off; off >>= 1) {
            a0 += __shfl_down(a0, off);
            a1 += __shfl_down(a1, off);
        }
        if ((tid & 63) == 0) { r0[tid >> 6] = a0; r1[tid >> 6] = a1; }
        __syncthreads();
        if (tid == 0) {
            float x0 = 0.f, x1 = 0.f;
            for (int i = 0; i < 8; ++i) { x0 += r0[i]; x1 += r1[i]; }
            cls_out[b * CLS_ + 0] = x0 + cls_b[0];
            cls_out[b * CLS_ + 1] = x1 + cls_b[1];
        }
    } else if (bx < 320) {               // ---- tag init to b2 ----
        int i = (bx - 128) * 512 + tid;  // < 98304 exactly
        tag[i] = b2[i % TOK_];
    } else if (bx < 352) {               // ---- ewt transpose+pad ----
        int j = (bx - 320) * 512 + tid;  // < 16384 exactly
        int n = j >> 7, k = j & 127;
        ewt[j] = (n < NF_ && k < NF_) ? f2bf(enr_w[k * NF_ + n]) : (unsigned short)0;
    } else {                             // ---- w1t[n][k] = bf16(w1[k][n]) ----
        __shared__ unsigned short tile[64][80];
        const int p = bx - 352;          // 168 = 14 ktiles x 12 ntiles
        const int kb = p % 14, nb = p / 14;
        const int k0 = kb * 64, n0 = nb * 64;
        const int kr = tid >> 3, cq = tid & 7;
        const int k = k0 + kr;
        const bool ok = k < (D_ + NF_);
        const float* src = w1 + (size_t)k * W_ + n0 + cq * 8;
        float4 v0 = ok ? *(const float4*)src       : make_float4(0.f,0.f,0.f,0.f);
        float4 v1 = ok ? *(const float4*)(src + 4) : make_float4(0.f,0.f,0.f,0.f);
        int nl = cq * 8;
        tile[nl+0][kr] = f2bf(v0.x); tile[nl+1][kr] = f2bf(v0.y);
        tile[nl+2][kr] = f2bf(v0.z); tile[nl+3][kr] = f2bf(v0.w);
        tile[nl+4][kr] = f2bf(v1.x); tile[nl+5][kr] = f2bf(v1.y);
        tile[nl+6][kr] = f2bf(v1.z); tile[nl+7][kr] = f2bf(v1.w);
        __syncthreads();
        const int nr = tid >> 3, kq = tid & 7;
        uint4 a = *(const uint4*)&tile[nr][kq * 8];
        *(uint4*)(w1t + (size_t)(n0 + nr) * KP_ + k0 + kq * 8) = a;
    }
}

// ======== pack: abf[row][0:768] = bf16(gathered seq row) or zeros ==============
// 8 rows/block, 32 lanes/row (24 floats each). Fully-dead 64-row tiles skipped.
__global__ __launch_bounds__(256)
void pack_kernel(const float* __restrict__ seq, const int* __restrict__ gidx,
                 const int* __restrict__ cnt, unsigned short* __restrict__ abf) {
    const int tid = threadIdx.x;
    const int r = tid >> 5;
    const int c = tid & 31;
    const int row = blockIdx.x * 8 + r;
    // skip rows in fully-dead 64-row tiles (main never reads their seq half)
    const int row0t = row & ~63;
    if ((row0t & (L_ - 1)) >= cnt[row >> 9]) return;
    const int gi = gidx[row];
    unsigned short* dst = abf + (size_t)row * KP_ + c * 24;
    if (gi >= 0) {
        const float* src = seq + (((size_t)(row >> 9) << 9) + gi) * D_ + c * 24;
#pragma unroll
        for (int jj = 0; jj < 3; ++jj) {
            float4 v0 = *(const float4*)(src + jj * 8);
            float4 v1 = *(const float4*)(src + jj * 8 + 4);
            uint4 wo = { pk2(v0.x, v0.y), pk2(v0.z, v0.w),
                         pk2(v1.x, v1.y), pk2(v1.z, v1.w) };
            *(uint4*)(dst + jj * 8) = wo;
        }
    } else {
        const uint4 z = {0u, 0u, 0u, 0u};
#pragma unroll
        for (int jj = 0; jj < 3; ++jj) *(uint4*)(dst + jj * 8) = z;
    }
}

// ======== enrichment GEMM -> abf[:,768:896] = bf16(relu(feat@enr_w+b)) ========
__global__ __launch_bounds__(256, 4)
void enrich_gemm(const float* __restrict__ feat, const unsigned short* __restrict__ ewt,
                 const float* __restrict__ eb, unsigned short* __restrict__ abf) {
    __shared__ unsigned short As[32 * 40];
    __shared__ unsigned short Bs[NFP_ * 32];

    const int tid  = threadIdx.x;
    const int lane = tid & 63;
    const int wv   = tid >> 6;
    const int row0 = blockIdx.x * 32;

    const int am = tid >> 3;
    const int ak = (tid & 7) * 4;
    const float* frow = feat + (size_t)(row0 + am) * NF_;

    const int bn = lane >> 2;
    const int bc = (lane & 3) ^ (bn & 3);

    f32x4 acc[2][2];
    const f32x4 zz = {0.f, 0.f, 0.f, 0.f};
    acc[0][0] = zz; acc[0][1] = zz; acc[1][0] = zz; acc[1][1] = zz;

    const int fl = lane & 15;
    const int fq = lane >> 4;
    const int sw = fq ^ (fl & 3);

#pragma unroll 1
    for (int kt = 0; kt < 4; ++kt) {
        const int k0 = kt * 32;
        __syncthreads();
        {
            unsigned int u0, u1;
            int k = k0 + ak;
            if (k < NF_) {
                float4 v = *(const float4*)(frow + k);
                u0 = pk2(v.x, v.y);
                u1 = pk2(v.z, v.w);
            } else { u0 = 0u; u1 = 0u; }
            *(unsigned int*)&As[am * 40 + ak]     = u0;
            *(unsigned int*)&As[am * 40 + ak + 2] = u1;
        }
#pragma unroll
        for (int it = 0; it < 2; ++it) {
            int nr0 = wv * 32 + it * 16;
            gload_lds16(ewt + (size_t)(nr0 + bn) * NFP_ + k0 + bc * 8, &Bs[nr0 * 32]);
        }
        __syncthreads();
        bf16x8 a0 = *(const bf16x8*)&As[fl * 40 + fq * 8];
        bf16x8 a1 = *(const bf16x8*)&As[(16 + fl) * 40 + fq * 8];
#pragma unroll
        for (int nt = 0; nt < 2; ++nt) {
            bf16x8 bfr = *(const bf16x8*)&Bs[(wv * 32 + nt * 16 + fl) * 32 + sw * 8];
            acc[0][nt] = __builtin_amdgcn_mfma_f32_16x16x32_bf16(a0, bfr, acc[0][nt], 0, 0, 0);
            acc[1][nt] = __builtin_amdgcn_mfma_f32_16x16x32_bf16(a1, bfr, acc[1][nt], 0, 0, 0);
        }
    }
#pragma unroll
    for (int nt = 0; nt < 2; ++nt) {
        int n = wv * 32 + nt * 16 + fl;
        float bias = (n < NF_) ? eb[n] : 0.f;
#pragma unroll
        for (int mt = 0; mt < 2; ++mt)
#pragma unroll
            for (int r = 0; r < 4; ++r) {
                float x = acc[mt][nt][r] + bias;
                x = x > 0.f ? x : 0.f;
                int m = row0 + mt * 16 + fq * 4 + r;
                abf[(size_t)m * KP_ + D_ + n] = f2bf(x);
            }
    }
}

// ======== main GEMM: BM=64, BN=128, BK=64; A pre-packed bf16; 4 blocks/CU ======
#define BM 64
#define BN 128

__global__ __launch_bounds__(256, 4)
void main_gemm(const unsigned short* __restrict__ abf, const int* __restrict__ cnt,
               const unsigned short* __restrict__ w1t,
               const float* __restrict__ b1, const float* __restrict__ w2,
               float* __restrict__ tag) {
    __shared__ unsigned short As[2][BM * 40];   // 10 KB: panel ks = k in [ks*32,+32)
    __shared__ unsigned short Bs[2][BN * 32];   // 16 KB: [n][32k], swizzled 16B chunks
    __shared__ float tagbuf[BM * TOK_];

    const int tid  = threadIdx.x;
    const int lane = tid & 63;
    const int wv   = tid >> 6;
    const int wvm  = wv >> 1, wvn = wv & 1;     // 2x2 wave grid: 32m x 64n
    // XCD swizzle: 6 n-siblings of each m-tile on the same XCD residue
    const int g    = blockIdx.x;                // grid 3072 = 8 xcd x 384
    const int j    = g >> 3;
    const int nblk = j % 6;
    const int mblk = (j / 6) * 8 + (g & 7);
    const int row0 = mblk * BM;
    const int n0   = nblk * BN;

    for (int i = tid; i < BM * TOK_; i += 256) tagbuf[i] = 0.f;

    // invalid-tile skip: in-batch rows >= cnt[batch] -> only enriched K-slice
    const int kt0 = ((row0 & (L_ - 1)) < cnt[row0 >> 9]) ? 0 : 12;

    // A copy ids: thread -> (row am, 16-short segment aq); branchless, contiguous
    const int am = tid >> 2;
    const int aq = tid & 3;
    const unsigned short* arow = abf + (size_t)(row0 + am) * KP_;

    // B staging lane ids
    const int bn = lane >> 2;
    const int bc = (lane & 3) ^ (bn & 3);

    f32x4 acc[2][4];
    const f32x4 zz = {0.f, 0.f, 0.f, 0.f};
#pragma unroll
    for (int i = 0; i < 2; ++i)
#pragma unroll
        for (int jn = 0; jn < 4; ++jn) acc[i][jn] = zz;

    const int fl = lane & 15;
    const int fq = lane >> 4;
    const int sw = fq ^ (fl & 3);

#pragma unroll 1
    for (int kt = kt0; kt < 14; ++kt) {
        const int k0 = kt * 64;
        __syncthreads();
        // ---- B DMA first (async global->LDS): 128 rows x 2 half-panels ----
#pragma unroll
        for (int h = 0; h < 2; ++h)
#pragma unroll
            for (int it = 0; it < 2; ++it) {
                int nr0 = wv * 32 + it * 16;
                gload_lds16(w1t + (size_t)(n0 + nr0 + bn) * KP_ + k0 + h * 32 + bc * 8,
                            &Bs[h][nr0 * 32]);
            }
        // ---- A copy: 16 contiguous bf16 (32 B) per thread, L2-hit ----
        {
            const unsigned short* p = arow + k0 + aq * 16;
            uint4 w0  = *(const uint4*)(p + 0);
            uint4 w1v = *(const uint4*)(p + 8);
            unsigned short* dst = &As[aq >> 1][am * 40 + (aq & 1) * 16];
            *(uint4*)(dst + 0) = w0;
            *(uint4*)(dst + 8) = w1v;
        }
        __syncthreads();
        // ---- compute: 2 k-steps x 8 MFMA per wave ----
#pragma unroll
        for (int ks = 0; ks < 2; ++ks) {
            bf16x8 af[2], bfr[4];
#pragma unroll
            for (int mt = 0; mt < 2; ++mt)
                af[mt] = *(const bf16x8*)&As[ks][(wvm * 32 + mt * 16 + fl) * 40 + fq * 8];
#pragma unroll
            for (int nt = 0; nt < 4; ++nt)
                bfr[nt] = *(const bf16x8*)&Bs[ks][(wvn * 64 + nt * 16 + fl) * 32 + sw * 8];
#pragma unroll
            for (int mt = 0; mt < 2; ++mt)
#pragma unroll
                for (int nt = 0; nt < 4; ++nt)
                    acc[mt][nt] = __builtin_amdgcn_mfma_f32_16x16x32_bf16(af[mt], bfr[nt], acc[mt][nt], 0, 0, 0);
        }
    }

    // ---- epilogue: h = relu(acc+b1); tag partial = h@w2; LDS then global atomics
    float b1v[4], w2v[4][TOK_];
#pragma unroll
    for (int nt = 0; nt < 4; ++nt) {
        int n = n0 + wvn * 64 + nt * 16 + fl;
        b1v[nt] = b1[n];
#pragma unroll
        for (int t = 0; t < TOK_; ++t) w2v[nt][t] = w2[n * TOK_ + t];
    }
#pragma unroll
    for (int mt = 0; mt < 2; ++mt)
#pragma unroll
        for (int r = 0; r < 4; ++r) {
            float s[TOK_] = {0.f, 0.f, 0.f};
#pragma unroll
            for (int nt = 0; nt < 4; ++nt) {
                float h = acc[mt][nt][r] + b1v[nt];
                h = h > 0.f ? h : 0.f;
#pragma unroll
                for (int t = 0; t < TOK_; ++t) s[t] += h * w2v[nt][t];
            }
#pragma unroll
            for (int off = 8; off; off >>= 1)
#pragma unroll
                for (int t = 0; t < TOK_; ++t) s[t] += __shfl_down(s[t], off, 16);
            if (fl == 0) {
                int m = wvm * 32 + mt * 16 + fq * 4 + r;
#pragma unroll
                for (int t = 0; t < TOK_; ++t) atomicAdd(&tagbuf[m * TOK_ + t], s[t]);
            }
        }
    __syncthreads();
    for (int i = tid; i < BM * TOK_; i += 256)
        atomicAdd(&tag[(size_t)row0 * TOK_ + i], tagbuf[i]);
}

extern "C" void kernel_launch(void* const* d_in, const int* in_sizes, int n_in,
                              void* d_out, int out_size, void* d_ws, size_t ws_size,
                              hipStream_t stream) {
    const float* seq   = (const float*)d_in[0];
    const float* feat  = (const float*)d_in[1];
    const int*   valid = (const int*)d_in[2];
    const float* enr_w = (const float*)d_in[3];
    const float* enr_b = (const float*)d_in[4];
    const float* w1    = (const float*)d_in[5];
    const float* b1    = (const float*)d_in[6];
    const float* w2    = (const float*)d_in[7];
    const float* b2    = (const float*)d_in[8];
    const float* cls_w = (const float*)d_in[9];
    const float* cls_b = (const float*)d_in[10];

    float* out = (float*)d_out;
    float* cls_out = out;                  // [64,2]
    float* tag_out = out + B_ * CLS_;      // [32768,3]

    // ws: w1t | ewt | abf | gidx | cnt  (~60.2 MB)
    unsigned short* w1t  = (unsigned short*)d_ws;                 // 768*896*2 B
    unsigned short* ewt  = w1t + (size_t)W_ * KP_;                // 128*128*2 B
    unsigned short* abf  = ewt + (size_t)NFP_ * NFP_;             // 32768*896*2 B
    int*            gidx = (int*)(abf + (size_t)MTOT_ * KP_);     // 32768*4 B
    int*            cnt  = gidx + MTOT_;                          // 64*4 B

    setup_kernel<<<520, 512, 0, stream>>>(valid, gidx, cnt, seq, cls_w, cls_b, cls_out,
                                          b2, tag_out, enr_w, ewt, w1, w1t);
    pack_kernel<<<MTOT_ / 8, 256, 0, stream>>>(seq, gidx, cnt, abf);
    enrich_gemm<<<MTOT_ / 32, 256, 0, stream>>>(feat, ewt, enr_b, abf);
    main_gemm<<<3072, 256, 0, stream>>>(abf, cnt, w1t, b1, w2, tag_out);
}

// Round 14
// 247.984 us; speedup vs baseline: 1.2298x; 1.0386x over previous
//
#include <hip/hip_runtime.h>
#include <hip/hip_bf16.h>

#define B_    64
#define L_    512
#define D_    768
#define NF_   100
#define W_    768
#define TOK_  3
#define CLS_  2
#define MTOT_ (B_ * L_)   // 32768
#define KP_   896         // padded K (768 seq + 128 padded enr)
#define NFP_  128         // padded NF

typedef __attribute__((ext_vector_type(8))) short  bf16x8;
typedef __attribute__((ext_vector_type(4))) float  f32x4;

__device__ __forceinline__ unsigned short f2bf(float f) {
    union { float f; unsigned int u; } v; v.f = f;
    unsigned int u = v.u;
    u += 0x7fffu + ((u >> 16) & 1u);   // RNE
    return (unsigned short)(u >> 16);
}

__device__ __forceinline__ unsigned int pk2(float x, float y) {
    __hip_bfloat162 h = __float22bfloat162_rn(make_float2(x, y)); // v_cvt_pk_bf16_f32
    return *(unsigned int*)&h;
}

typedef __attribute__((address_space(3))) unsigned int        lds_uint;
typedef const __attribute__((address_space(1))) unsigned int  gbl_uint;

__device__ __forceinline__ void gload_lds16(const void* gp, void* lp) {
    __builtin_amdgcn_global_load_lds((gbl_uint*)gp, (lds_uint*)lp, 16, 0, 0);
}

// ======== setup: compact+cnt | cls | tag init | ewt | w1 transpose =============
__global__ void setup_kernel(const int* __restrict__ valid, int* __restrict__ gidx,
                             int* __restrict__ cnt,
                             const float* __restrict__ seq, const float* __restrict__ cls_w,
                             const float* __restrict__ cls_b, float* __restrict__ cls_out,
                             const float* __restrict__ b2, float* __restrict__ tag,
                             const float* __restrict__ enr_w, unsigned short* __restrict__ ewt,
                             const float* __restrict__ w1, unsigned short* __restrict__ w1t) {
    const int bx = blockIdx.x, tid = threadIdx.x;
    if (bx < 64) {                       // ---- valid compaction + count ----
        __shared__ int s[L_];
        int v = valid[bx * L_ + tid];
        s[tid] = v;
        __syncthreads();
        for (int off = 1; off < L_; off <<= 1) {
            int x = (tid >= off) ? s[tid - off] : 0;
            __syncthreads();
            s[tid] += x;
            __syncthreads();
        }
        int inc = s[tid];
        if (tid == L_ - 1) cnt[bx] = inc;
        gidx[bx * L_ + tid] = -1;
        __syncthreads();
        if (v) gidx[bx * L_ + inc - 1] = tid;
    } else if (bx < 128) {               // ---- cls head ----
        const int b = bx - 64;
        __shared__ float r0[8], r1[8];
        const float* row = seq + (size_t)b * L_ * D_;
        float a0 = 0.f, a1 = 0.f;
        for (int d = tid; d < D_; d += 512) {
            float x = row[d];
            a0 += x * cls_w[d * CLS_ + 0];
            a1 += x * cls_w[d * CLS_ + 1];
        }
        for (int off = 32; off; off >>= 1) {
            a0 += __shfl_down(a0, off);
            a1 += __shfl_down(a1, off);
        }
        if ((tid & 63) == 0) { r0[tid >> 6] = a0; r1[tid >> 6] = a1; }
        __syncthreads();
        if (tid == 0) {
            float x0 = 0.f, x1 = 0.f;
            for (int i = 0; i < 8; ++i) { x0 += r0[i]; x1 += r1[i]; }
            cls_out[b * CLS_ + 0] = x0 + cls_b[0];
            cls_out[b * CLS_ + 1] = x1 + cls_b[1];
        }
    } else if (bx < 320) {               // ---- tag init to b2 ----
        int i = (bx - 128) * 512 + tid;  // < 98304 exactly
        tag[i] = b2[i % TOK_];
    } else if (bx < 352) {               // ---- ewt transpose+pad ----
        int j = (bx - 320) * 512 + tid;  // < 16384 exactly
        int n = j >> 7, k = j & 127;
        ewt[j] = (n < NF_ && k < NF_) ? f2bf(enr_w[k * NF_ + n]) : (unsigned short)0;
    } else {                             // ---- w1t[n][k] = bf16(w1[k][n]) ----
        __shared__ unsigned short tile[64][80];
        const int p = bx - 352;          // 168 = 14 ktiles x 12 ntiles
        const int kb = p % 14, nb = p / 14;
        const int k0 = kb * 64, n0 = nb * 64;
        const int kr = tid >> 3, cq = tid & 7;
        const int k = k0 + kr;
        const bool ok = k < (D_ + NF_);
        const float* src = w1 + (size_t)k * W_ + n0 + cq * 8;
        float4 v0 = ok ? *(const float4*)src       : make_float4(0.f,0.f,0.f,0.f);
        float4 v1 = ok ? *(const float4*)(src + 4) : make_float4(0.f,0.f,0.f,0.f);
        int nl = cq * 8;
        tile[nl+0][kr] = f2bf(v0.x); tile[nl+1][kr] = f2bf(v0.y);
        tile[nl+2][kr] = f2bf(v0.z); tile[nl+3][kr] = f2bf(v0.w);
        tile[nl+4][kr] = f2bf(v1.x); tile[nl+5][kr] = f2bf(v1.y);
        tile[nl+6][kr] = f2bf(v1.z); tile[nl+7][kr] = f2bf(v1.w);
        __syncthreads();
        const int nr = tid >> 3, kq = tid & 7;
        uint4 a = *(const uint4*)&tile[nr][kq * 8];
        *(uint4*)(w1t + (size_t)(n0 + nr) * KP_ + k0 + kq * 8) = a;
    }
}

// ======== pack (abf[:,0:768]) + enrich (abf[:,768:896]) in one launch ==========
__global__ __launch_bounds__(256)
void pack_enrich(const float* __restrict__ seq, const int* __restrict__ gidx,
                 const int* __restrict__ cnt, const float* __restrict__ feat,
                 const unsigned short* __restrict__ ewt, const float* __restrict__ eb,
                 unsigned short* __restrict__ abf) {
    const int bx = blockIdx.x, tid = threadIdx.x;
    if (bx < MTOT_ / 8) {
        // ---- pack: 8 rows/block, 32 lanes/row (24 floats each) ----
        const int r = tid >> 5;
        const int c = tid & 31;
        const int row = bx * 8 + r;
        const int row0t = row & ~63;     // skip rows in fully-dead 64-row tiles
        if ((row0t & (L_ - 1)) >= cnt[row >> 9]) return;
        const int gi = gidx[row];
        unsigned short* dst = abf + (size_t)row * KP_ + c * 24;
        if (gi >= 0) {
            const float* src = seq + (((size_t)(row >> 9) << 9) + gi) * D_ + c * 24;
#pragma unroll
            for (int jj = 0; jj < 3; ++jj) {
                float4 v0 = *(const float4*)(src + jj * 8);
                float4 v1 = *(const float4*)(src + jj * 8 + 4);
                uint4 wo = { pk2(v0.x, v0.y), pk2(v0.z, v0.w),
                             pk2(v1.x, v1.y), pk2(v1.z, v1.w) };
                *(uint4*)(dst + jj * 8) = wo;
            }
        } else {
            const uint4 z = {0u, 0u, 0u, 0u};
#pragma unroll
            for (int jj = 0; jj < 3; ++jj) *(uint4*)(dst + jj * 8) = z;
        }
    } else {
        // ---- enrich GEMM: 32 rows/block -> abf[:,768:896] ----
        __shared__ unsigned short As[32 * 40];
        __shared__ unsigned short Bs[NFP_ * 32];
        const int lane = tid & 63;
        const int wv   = tid >> 6;
        const int row0 = (bx - MTOT_ / 8) * 32;
        const int am = tid >> 3;
        const int ak = (tid & 7) * 4;
        const float* frow = feat + (size_t)(row0 + am) * NF_;
        const int bn = lane >> 2;
        const int bc = (lane & 3) ^ (bn & 3);
        f32x4 acc[2][2];
        const f32x4 zz = {0.f, 0.f, 0.f, 0.f};
        acc[0][0] = zz; acc[0][1] = zz; acc[1][0] = zz; acc[1][1] = zz;
        const int fl = lane & 15;
        const int fq = lane >> 4;
        const int sw = fq ^ (fl & 3);
#pragma unroll 1
        for (int kt = 0; kt < 4; ++kt) {
            const int k0 = kt * 32;
            __syncthreads();
            {
                unsigned int u0, u1;
                int k = k0 + ak;
                if (k < NF_) {
                    float4 v = *(const float4*)(frow + k);
                    u0 = pk2(v.x, v.y);
                    u1 = pk2(v.z, v.w);
                } else { u0 = 0u; u1 = 0u; }
                *(unsigned int*)&As[am * 40 + ak]     = u0;
                *(unsigned int*)&As[am * 40 + ak + 2] = u1;
            }
#pragma unroll
            for (int it = 0; it < 2; ++it) {
                int nr0 = wv * 32 + it * 16;
                gload_lds16(ewt + (size_t)(nr0 + bn) * NFP_ + k0 + bc * 8, &Bs[nr0 * 32]);
            }
            __syncthreads();
            bf16x8 a0 = *(const bf16x8*)&As[fl * 40 + fq * 8];
            bf16x8 a1 = *(const bf16x8*)&As[(16 + fl) * 40 + fq * 8];
#pragma unroll
            for (int nt = 0; nt < 2; ++nt) {
                bf16x8 bfr = *(const bf16x8*)&Bs[(wv * 32 + nt * 16 + fl) * 32 + sw * 8];
                acc[0][nt] = __builtin_amdgcn_mfma_f32_16x16x32_bf16(a0, bfr, acc[0][nt], 0, 0, 0);
                acc[1][nt] = __builtin_amdgcn_mfma_f32_16x16x32_bf16(a1, bfr, acc[1][nt], 0, 0, 0);
            }
        }
#pragma unroll
        for (int nt = 0; nt < 2; ++nt) {
            int n = wv * 32 + nt * 16 + fl;
            float bias = (n < NF_) ? eb[n] : 0.f;
#pragma unroll
            for (int mt = 0; mt < 2; ++mt)
#pragma unroll
                for (int r = 0; r < 4; ++r) {
                    float x = acc[mt][nt][r] + bias;
                    x = x > 0.f ? x : 0.f;
                    int m = row0 + mt * 16 + fq * 4 + r;
                    abf[(size_t)m * KP_ + D_ + n] = f2bf(x);
                }
        }
    }
}

// ======== main GEMM: BM=64, BN=128, BK=64; ALL staging via DMA; 1 barrier/kt ===
// Double-buffered A+B, prefetch distance 1: the barrier's vmcnt(0) drain lands
// AFTER compute has covered the prefetch latency. LDS unpadded + XOR chunk
// swizzle (slot = chunk ^ (row&7)) -> 2-way-free frag reads. 3 blocks/CU.
#define BM 64
#define BN 128

__global__ __launch_bounds__(256, 3)
void main_gemm(const unsigned short* __restrict__ abf, const int* __restrict__ cnt,
               const unsigned short* __restrict__ w1t,
               const float* __restrict__ b1, const float* __restrict__ w2,
               float* __restrict__ tag) {
    __shared__ unsigned short As[2][BM * 64];   // 2 x 8 KB
    __shared__ unsigned short Bs[2][BN * 64];   // 2 x 16 KB
    __shared__ float tagbuf[BM * TOK_];

    const int tid  = threadIdx.x;
    const int lane = tid & 63;
    const int wv   = tid >> 6;
    const int wvm  = wv >> 1, wvn = wv & 1;     // 2x2 wave grid: 32m x 64n
    // XCD swizzle: 6 n-siblings of each m-tile on the same XCD residue
    const int g    = blockIdx.x;                // grid 3072 = 8 xcd x 384
    const int j    = g >> 3;
    const int nblk = j % 6;
    const int mblk = (j / 6) * 8 + (g & 7);
    const int row0 = mblk * BM;
    const int n0   = nblk * BN;

    for (int i = tid; i < BM * TOK_; i += 256) tagbuf[i] = 0.f;

    const int kt0 = ((row0 & (L_ - 1)) < cnt[row0 >> 9]) ? 0 : 12;

    // DMA lane mapping: lane -> (row-in-group dr, LDS slot-chunk dc);
    // global chunk is XOR-swizzled so frag reads are conflict-free.
    const int dr  = lane >> 3;          // 0..7
    const int dc  = lane & 7;           // LDS slot
    const int dcx = dc ^ dr;            // global chunk = slot ^ (row&7)

    const int fl = lane & 15;
    const int fq = lane >> 4;

    f32x4 acc[2][4];
    const f32x4 zz = {0.f, 0.f, 0.f, 0.f};
#pragma unroll
    for (int i = 0; i < 2; ++i)
#pragma unroll
        for (int jn = 0; jn < 4; ++jn) acc[i][jn] = zz;

    // ---- prologue: fire A(kt0), B(kt0) into buf 0 ----
    {
        const int k0 = kt0 * 64;
#pragma unroll
        for (int it = 0; it < 2; ++it) {    // A: 2 groups of 8 rows per wave
            int nr0 = wv * 16 + it * 8;
            gload_lds16(abf + (size_t)(row0 + nr0 + dr) * KP_ + k0 + dcx * 8,
                        &As[0][nr0 * 64]);
        }
#pragma unroll
        for (int it = 0; it < 4; ++it) {    // B: 4 groups of 8 rows per wave
            int nr0 = wv * 32 + it * 8;
            gload_lds16(w1t + (size_t)(n0 + nr0 + dr) * KP_ + k0 + dcx * 8,
                        &Bs[0][nr0 * 64]);
        }
    }
    __syncthreads();

    // ---- K-loop: fire (kt+1) -> compute(kt) -> 1 barrier ----
#pragma unroll 1
    for (int kt = kt0; kt < 14; ++kt) {
        const int buf = kt & 1;
        if (kt + 1 < 14) {
            const int kn = (kt + 1) * 64;
#pragma unroll
            for (int it = 0; it < 2; ++it) {
                int nr0 = wv * 16 + it * 8;
                gload_lds16(abf + (size_t)(row0 + nr0 + dr) * KP_ + kn + dcx * 8,
                            &As[buf ^ 1][nr0 * 64]);
            }
#pragma unroll
            for (int it = 0; it < 4; ++it) {
                int nr0 = wv * 32 + it * 8;
                gload_lds16(w1t + (size_t)(n0 + nr0 + dr) * KP_ + kn + dcx * 8,
                            &Bs[buf ^ 1][nr0 * 64]);
            }
        }
        // ---- compute kt: 2 k-steps x 8 MFMA per wave ----
#pragma unroll
        for (int ks = 0; ks < 2; ++ks) {
            bf16x8 af[2], bfr[4];
#pragma unroll
            for (int mt = 0; mt < 2; ++mt) {
                int m = wvm * 32 + mt * 16 + fl;
                int slot = (ks * 4 + fq) ^ (fl & 7);
                af[mt] = *(const bf16x8*)&As[buf][m * 64 + slot * 8];
            }
#pragma unroll
            for (int nt = 0; nt < 4; ++nt) {
                int n = wvn * 64 + nt * 16 + fl;
                int slot = (ks * 4 + fq) ^ (fl & 7);
                bfr[nt] = *(const bf16x8*)&Bs[buf][n * 64 + slot * 8];
            }
#pragma unroll
            for (int mt = 0; mt < 2; ++mt)
#pragma unroll
                for (int nt = 0; nt < 4; ++nt)
                    acc[mt][nt] = __builtin_amdgcn_mfma_f32_16x16x32_bf16(af[mt], bfr[nt], acc[mt][nt], 0, 0, 0);
        }
        __syncthreads();   // drains (kt+1) DMA (latency covered by compute) + read fence
    }

    // ---- epilogue: h = relu(acc+b1); tag partial = h@w2; LDS then global atomics
    float b1v[4], w2v[4][TOK_];
#pragma unroll
    for (int nt = 0; nt < 4; ++nt) {
        int n = n0 + wvn * 64 + nt * 16 + fl;
        b1v[nt] = b1[n];
#pragma unroll
        for (int t = 0; t < TOK_; ++t) w2v[nt][t] = w2[n * TOK_ + t];
    }
#pragma unroll
    for (int mt = 0; mt < 2; ++mt)
#pragma unroll
        for (int r = 0; r < 4; ++r) {
            float s[TOK_] = {0.f, 0.f, 0.f};
#pragma unroll
            for (int nt = 0; nt < 4; ++nt) {
                float h = acc[mt][nt][r] + b1v[nt];
                h = h > 0.f ? h : 0.f;
#pragma unroll
                for (int t = 0; t < TOK_; ++t) s[t] += h * w2v[nt][t];
            }
#pragma unroll
            for (int off = 8; off; off >>= 1)
#pragma unroll
                for (int t = 0; t < TOK_; ++t) s[t] += __shfl_down(s[t], off, 16);
            if (fl == 0) {
                int m = wvm * 32 + mt * 16 + fq * 4 + r;
#pragma unroll
                for (int t = 0; t < TOK_; ++t) atomicAdd(&tagbuf[m * TOK_ + t], s[t]);
            }
        }
    __syncthreads();
    for (int i = tid; i < BM * TOK_; i += 256)
        atomicAdd(&tag[(size_t)row0 * TOK_ + i], tagbuf[i]);
}

extern "C" void kernel_launch(void* const* d_in, const int* in_sizes, int n_in,
                              void* d_out, int out_size, void* d_ws, size_t ws_size,
                              hipStream_t stream) {
    const float* seq   = (const float*)d_in[0];
    const float* feat  = (const float*)d_in[1];
    const int*   valid = (const int*)d_in[2];
    const float* enr_w = (const float*)d_in[3];
    const float* enr_b = (const float*)d_in[4];
    const float* w1    = (const float*)d_in[5];
    const float* b1    = (const float*)d_in[6];
    const float* w2    = (const float*)d_in[7];
    const float* b2    = (const float*)d_in[8];
    const float* cls_w = (const float*)d_in[9];
    const float* cls_b = (const float*)d_in[10];

    float* out = (float*)d_out;
    float* cls_out = out;                  // [64,2]
    float* tag_out = out + B_ * CLS_;      // [32768,3]

    // ws: w1t | ewt | abf | gidx | cnt  (~60.2 MB)
    unsigned short* w1t  = (unsigned short*)d_ws;                 // 768*896*2 B
    unsigned short* ewt  = w1t + (size_t)W_ * KP_;                // 128*128*2 B
    unsigned short* abf  = ewt + (size_t)NFP_ * NFP_;             // 32768*896*2 B
    int*            gidx = (int*)(abf + (size_t)MTOT_ * KP_);     // 32768*4 B
    int*            cnt  = gidx + MTOT_;                          // 64*4 B

    setup_kernel<<<520, 512, 0, stream>>>(valid, gidx, cnt, seq, cls_w, cls_b, cls_out,
                                          b2, tag_out, enr_w, ewt, w1, w1t);
    pack_enrich<<<MTOT_ / 8 + MTOT_ / 32, 256, 0, stream>>>(seq, gidx, cnt, feat,
                                                            ewt, enr_b, abf);
    main_gemm<<<3072, 256, 0, stream>>>(abf, cnt, w1t, b1, w2, tag_out);
}

// Round 15
// 232.260 us; speedup vs baseline: 1.3130x; 1.0677x over previous
//
#include <hip/hip_runtime.h>
#include <hip/hip_bf16.h>

#define B_    64
#define L_    512
#define D_    768
#define NF_   100
#define W_    768
#define TOK_  3
#define CLS_  2
#define MTOT_ (B_ * L_)   // 32768
#define KP_   896         // padded K (768 seq + 128 padded enr)
#define NFP_  128         // padded NF

typedef __attribute__((ext_vector_type(8))) short  bf16x8;
typedef __attribute__((ext_vector_type(4))) float  f32x4;

__device__ __forceinline__ unsigned short f2bf(float f) {
    union { float f; unsigned int u; } v; v.f = f;
    unsigned int u = v.u;
    u += 0x7fffu + ((u >> 16) & 1u);   // RNE
    return (unsigned short)(u >> 16);
}

__device__ __forceinline__ unsigned int pk2(float x, float y) {
    __hip_bfloat162 h = __float22bfloat162_rn(make_float2(x, y)); // v_cvt_pk_bf16_f32
    return *(unsigned int*)&h;
}

typedef __attribute__((address_space(3))) unsigned int        lds_uint;
typedef const __attribute__((address_space(1))) unsigned int  gbl_uint;

__device__ __forceinline__ void gload_lds16(const void* gp, void* lp) {
    __builtin_amdgcn_global_load_lds((gbl_uint*)gp, (lds_uint*)lp, 16, 0, 0);
}

// ======== setup: compact+cnt | cls | tag init | ewt | w1 transpose =============
__global__ void setup_kernel(const int* __restrict__ valid, int* __restrict__ gidx,
                             int* __restrict__ cnt,
                             const float* __restrict__ seq, const float* __restrict__ cls_w,
                             const float* __restrict__ cls_b, float* __restrict__ cls_out,
                             const float* __restrict__ b2, float* __restrict__ tag,
                             const float* __restrict__ enr_w, unsigned short* __restrict__ ewt,
                             const float* __restrict__ w1, unsigned short* __restrict__ w1t) {
    const int bx = blockIdx.x, tid = threadIdx.x;
    if (bx < 64) {                       // ---- valid compaction + count ----
        __shared__ int s[L_];
        int v = valid[bx * L_ + tid];
        s[tid] = v;
        __syncthreads();
        for (int off = 1; off < L_; off <<= 1) {
            int x = (tid >= off) ? s[tid - off] : 0;
            __syncthreads();
            s[tid] += x;
            __syncthreads();
        }
        int inc = s[tid];
        if (tid == L_ - 1) cnt[bx] = inc;
        gidx[bx * L_ + tid] = -1;
        __syncthreads();
        if (v) gidx[bx * L_ + inc - 1] = tid;
    } else if (bx < 128) {               // ---- cls head ----
        const int b = bx - 64;
        __shared__ float r0[8], r1[8];
        const float* row = seq + (size_t)b * L_ * D_;
        float a0 = 0.f, a1 = 0.f;
        for (int d = tid; d < D_; d += 512) {
            float x = row[d];
            a0 += x * cls_w[d * CLS_ + 0];
            a1 += x * cls_w[d * CLS_ + 1];
        }
        for (int off = 32; off; off >>= 1) {
            a0 += __shfl_down(a0, off);
            a1 += __shfl_down(a1, off);
        }
        if ((tid & 63) == 0) { r0[tid >> 6] = a0; r1[tid >> 6] = a1; }
        __syncthreads();
        if (tid == 0) {
            float x0 = 0.f, x1 = 0.f;
            for (int i = 0; i < 8; ++i) { x0 += r0[i]; x1 += r1[i]; }
            cls_out[b * CLS_ + 0] = x0 + cls_b[0];
            cls_out[b * CLS_ + 1] = x1 + cls_b[1];
        }
    } else if (bx < 320) {               // ---- tag init to b2 ----
        int i = (bx - 128) * 512 + tid;  // < 98304 exactly
        tag[i] = b2[i % TOK_];
    } else if (bx < 352) {               // ---- ewt transpose+pad ----
        int j = (bx - 320) * 512 + tid;  // < 16384 exactly
        int n = j >> 7, k = j & 127;
        ewt[j] = (n < NF_ && k < NF_) ? f2bf(enr_w[k * NF_ + n]) : (unsigned short)0;
    } else {                             // ---- w1t[n][k] = bf16(w1[k][n]) ----
        __shared__ unsigned short tile[64][80];
        const int p = bx - 352;          // 168 = 14 ktiles x 12 ntiles
        const int kb = p % 14, nb = p / 14;
        const int k0 = kb * 64, n0 = nb * 64;
        const int kr = tid >> 3, cq = tid & 7;
        const int k = k0 + kr;
        const bool ok = k < (D_ + NF_);
        const float* src = w1 + (size_t)k * W_ + n0 + cq * 8;
        float4 v0 = ok ? *(const float4*)src       : make_float4(0.f,0.f,0.f,0.f);
        float4 v1 = ok ? *(const float4*)(src + 4) : make_float4(0.f,0.f,0.f,0.f);
        int nl = cq * 8;
        tile[nl+0][kr] = f2bf(v0.x); tile[nl+1][kr] = f2bf(v0.y);
        tile[nl+2][kr] = f2bf(v0.z); tile[nl+3][kr] = f2bf(v0.w);
        tile[nl+4][kr] = f2bf(v1.x); tile[nl+5][kr] = f2bf(v1.y);
        tile[nl+6][kr] = f2bf(v1.z); tile[nl+7][kr] = f2bf(v1.w);
        __syncthreads();
        const int nr = tid >> 3, kq = tid & 7;
        uint4 a = *(const uint4*)&tile[nr][kq * 8];
        *(uint4*)(w1t + (size_t)(n0 + nr) * KP_ + k0 + kq * 8) = a;
    }
}

// ======== pack (abf[:,0:768]) + enrich (abf[:,768:896]) in one launch ==========
__global__ __launch_bounds__(256)
void pack_enrich(const float* __restrict__ seq, const int* __restrict__ gidx,
                 const int* __restrict__ cnt, const float* __restrict__ feat,
                 const unsigned short* __restrict__ ewt, const float* __restrict__ eb,
                 unsigned short* __restrict__ abf) {
    const int bx = blockIdx.x, tid = threadIdx.x;
    if (bx < MTOT_ / 8) {
        // ---- pack: 8 rows/block, 32 lanes/row (24 floats each) ----
        const int r = tid >> 5;
        const int c = tid & 31;
        const int row = bx * 8 + r;
        const int row0t = row & ~127;    // skip rows in fully-dead 128-row tiles
        if ((row0t & (L_ - 1)) >= cnt[row >> 9]) return;
        const int gi = gidx[row];
        unsigned short* dst = abf + (size_t)row * KP_ + c * 24;
        if (gi >= 0) {
            const float* src = seq + (((size_t)(row >> 9) << 9) + gi) * D_ + c * 24;
#pragma unroll
            for (int jj = 0; jj < 3; ++jj) {
                float4 v0 = *(const float4*)(src + jj * 8);
                float4 v1 = *(const float4*)(src + jj * 8 + 4);
                uint4 wo = { pk2(v0.x, v0.y), pk2(v0.z, v0.w),
                             pk2(v1.x, v1.y), pk2(v1.z, v1.w) };
                *(uint4*)(dst + jj * 8) = wo;
            }
        } else {
            const uint4 z = {0u, 0u, 0u, 0u};
#pragma unroll
            for (int jj = 0; jj < 3; ++jj) *(uint4*)(dst + jj * 8) = z;
        }
    } else {
        // ---- enrich GEMM: 32 rows/block -> abf[:,768:896] ----
        __shared__ unsigned short As[32 * 40];
        __shared__ unsigned short Bs[NFP_ * 32];
        const int lane = tid & 63;
        const int wv   = tid >> 6;
        const int row0 = (bx - MTOT_ / 8) * 32;
        const int am = tid >> 3;
        const int ak = (tid & 7) * 4;
        const float* frow = feat + (size_t)(row0 + am) * NF_;
        const int bn = lane >> 2;
        const int bc = (lane & 3) ^ (bn & 3);
        f32x4 acc[2][2];
        const f32x4 zz = {0.f, 0.f, 0.f, 0.f};
        acc[0][0] = zz; acc[0][1] = zz; acc[1][0] = zz; acc[1][1] = zz;
        const int fl = lane & 15;
        const int fq = lane >> 4;
        const int sw = fq ^ (fl & 3);
#pragma unroll 1
        for (int kt = 0; kt < 4; ++kt) {
            const int k0 = kt * 32;
            __syncthreads();
            {
                unsigned int u0, u1;
                int k = k0 + ak;
                if (k < NF_) {
                    float4 v = *(const float4*)(frow + k);
                    u0 = pk2(v.x, v.y);
                    u1 = pk2(v.z, v.w);
                } else { u0 = 0u; u1 = 0u; }
                *(unsigned int*)&As[am * 40 + ak]     = u0;
                *(unsigned int*)&As[am * 40 + ak + 2] = u1;
            }
#pragma unroll
            for (int it = 0; it < 2; ++it) {
                int nr0 = wv * 32 + it * 16;
                gload_lds16(ewt + (size_t)(nr0 + bn) * NFP_ + k0 + bc * 8, &Bs[nr0 * 32]);
            }
            __syncthreads();
            bf16x8 a0 = *(const bf16x8*)&As[fl * 40 + fq * 8];
            bf16x8 a1 = *(const bf16x8*)&As[(16 + fl) * 40 + fq * 8];
#pragma unroll
            for (int nt = 0; nt < 2; ++nt) {
                bf16x8 bfr = *(const bf16x8*)&Bs[(wv * 32 + nt * 16 + fl) * 32 + sw * 8];
                acc[0][nt] = __builtin_amdgcn_mfma_f32_16x16x32_bf16(a0, bfr, acc[0][nt], 0, 0, 0);
                acc[1][nt] = __builtin_amdgcn_mfma_f32_16x16x32_bf16(a1, bfr, acc[1][nt], 0, 0, 0);
            }
        }
#pragma unroll
        for (int nt = 0; nt < 2; ++nt) {
            int n = wv * 32 + nt * 16 + fl;
            float bias = (n < NF_) ? eb[n] : 0.f;
#pragma unroll
            for (int mt = 0; mt < 2; ++mt)
#pragma unroll
                for (int r = 0; r < 4; ++r) {
                    float x = acc[mt][nt][r] + bias;
                    x = x > 0.f ? x : 0.f;
                    int m = row0 + mt * 16 + fq * 4 + r;
                    abf[(size_t)m * KP_ + D_ + n] = f2bf(x);
                }
        }
    }
}

// ======== main GEMM: m97 structure on packed operands ==========================
// BM=128, BN=128, BK=64; 4 waves of 64x64; A+B via global_load_lds w=16;
// single-buffer, 2 barriers/kt; zero-conflict XOR chunk swizzle (R14-measured).
// 32 KB staged per 128 MFMA/kt — 2x better MFMA/byte than R14.
#define BM 128
#define BN 128

__global__ __launch_bounds__(256, 3)
void main_gemm(const unsigned short* __restrict__ abf, const int* __restrict__ cnt,
               const unsigned short* __restrict__ w1t,
               const float* __restrict__ b1, const float* __restrict__ w2,
               float* __restrict__ tag) {
    __shared__ unsigned short As[BM * 64];   // 16 KB: row stride 64 shorts (8 chunks)
    __shared__ unsigned short Bs[BN * 64];   // 16 KB
    __shared__ float tagbuf[BM * TOK_];

    const int tid  = threadIdx.x;
    const int lane = tid & 63;
    const int wv   = tid >> 6;
    const int wvm  = wv >> 1, wvn = wv & 1;     // 2x2 wave grid: 64m x 64n
    // XCD swizzle: 6 n-siblings of each m-tile on the same XCD residue
    const int g    = blockIdx.x;                // grid 1536 = 8 xcd x 192
    const int j    = g >> 3;
    const int nblk = j % 6;
    const int mblk = (j / 6) * 8 + (g & 7);
    const int row0 = mblk * BM;
    const int n0   = nblk * BN;

    for (int i = tid; i < BM * TOK_; i += 256) tagbuf[i] = 0.f;

    const int kt0 = ((row0 & (L_ - 1)) < cnt[row0 >> 9]) ? 0 : 12;

    // DMA lane map (R14 zero-conflict): 8 rows x 8 chunks, slot = chunk ^ row
    const int dr  = lane >> 3;          // row in 8-group
    const int dc  = lane & 7;           // LDS slot
    const int dcx = dc ^ dr;            // global 16B chunk

    const int fl = lane & 15;
    const int fq = lane >> 4;

    f32x4 acc[4][4];
    const f32x4 zz = {0.f, 0.f, 0.f, 0.f};
#pragma unroll
    for (int i = 0; i < 4; ++i)
#pragma unroll
        for (int jn = 0; jn < 4; ++jn) acc[i][jn] = zz;

#pragma unroll 1
    for (int kt = kt0; kt < 14; ++kt) {
        const int k0 = kt * 64;
        __syncthreads();                 // everyone done reading LDS
        // ---- fire A+B DMA: 4+4 insts/wave, 8 rows each ----
#pragma unroll
        for (int it = 0; it < 4; ++it) {
            int nr0 = wv * 32 + it * 8;
            gload_lds16(abf + (size_t)(row0 + nr0 + dr) * KP_ + k0 + dcx * 8,
                        &As[nr0 * 64]);
            gload_lds16(w1t + (size_t)(n0 + nr0 + dr) * KP_ + k0 + dcx * 8,
                        &Bs[nr0 * 64]);
        }
        __syncthreads();                 // DMA drained (co-resident blocks hide it)
        // ---- compute: 2 k-steps x 16 MFMA ----
#pragma unroll
        for (int ks = 0; ks < 2; ++ks) {
            bf16x8 af[4], bfr[4];
#pragma unroll
            for (int mt = 0; mt < 4; ++mt) {
                int m = wvm * 64 + mt * 16 + fl;
                int slot = (ks * 4 + fq) ^ (m & 7);
                af[mt] = *(const bf16x8*)&As[m * 64 + slot * 8];
            }
#pragma unroll
            for (int nt = 0; nt < 4; ++nt) {
                int n = wvn * 64 + nt * 16 + fl;
                int slot = (ks * 4 + fq) ^ (n & 7);
                bfr[nt] = *(const bf16x8*)&Bs[n * 64 + slot * 8];
            }
#pragma unroll
            for (int mt = 0; mt < 4; ++mt)
#pragma unroll
                for (int nt = 0; nt < 4; ++nt)
                    acc[mt][nt] = __builtin_amdgcn_mfma_f32_16x16x32_bf16(af[mt], bfr[nt], acc[mt][nt], 0, 0, 0);
        }
    }

    // ---- epilogue: h = relu(acc+b1); tag partial = h@w2; LDS then global atomics
    float b1v[4], w2v[4][TOK_];
#pragma unroll
    for (int nt = 0; nt < 4; ++nt) {
        int n = n0 + wvn * 64 + nt * 16 + fl;
        b1v[nt] = b1[n];
#pragma unroll
        for (int t = 0; t < TOK_; ++t) w2v[nt][t] = w2[n * TOK_ + t];
    }
#pragma unroll
    for (int mt = 0; mt < 4; ++mt)
#pragma unroll
        for (int r = 0; r < 4; ++r) {
            float s[TOK_] = {0.f, 0.f, 0.f};
#pragma unroll
            for (int nt = 0; nt < 4; ++nt) {
                float h = acc[mt][nt][r] + b1v[nt];
                h = h > 0.f ? h : 0.f;
#pragma unroll
                for (int t = 0; t < TOK_; ++t) s[t] += h * w2v[nt][t];
            }
#pragma unroll
            for (int off = 8; off; off >>= 1)
#pragma unroll
                for (int t = 0; t < TOK_; ++t) s[t] += __shfl_down(s[t], off, 16);
            if (fl == 0) {
                int m = wvm * 64 + mt * 16 + fq * 4 + r;
#pragma unroll
                for (int t = 0; t < TOK_; ++t) atomicAdd(&tagbuf[m * TOK_ + t], s[t]);
            }
        }
    __syncthreads();
    for (int i = tid; i < BM * TOK_; i += 256)
        atomicAdd(&tag[(size_t)row0 * TOK_ + i], tagbuf[i]);
}

extern "C" void kernel_launch(void* const* d_in, const int* in_sizes, int n_in,
                              void* d_out, int out_size, void* d_ws, size_t ws_size,
                              hipStream_t stream) {
    const float* seq   = (const float*)d_in[0];
    const float* feat  = (const float*)d_in[1];
    const int*   valid = (const int*)d_in[2];
    const float* enr_w = (const float*)d_in[3];
    const float* enr_b = (const float*)d_in[4];
    const float* w1    = (const float*)d_in[5];
    const float* b1    = (const float*)d_in[6];
    const float* w2    = (const float*)d_in[7];
    const float* b2    = (const float*)d_in[8];
    const float* cls_w = (const float*)d_in[9];
    const float* cls_b = (const float*)d_in[10];

    float* out = (float*)d_out;
    float* cls_out = out;                  // [64,2]
    float* tag_out = out + B_ * CLS_;      // [32768,3]

    // ws: w1t | ewt | abf | gidx | cnt  (~60.2 MB)
    unsigned short* w1t  = (unsigned short*)d_ws;                 // 768*896*2 B
    unsigned short* ewt  = w1t + (size_t)W_ * KP_;                // 128*128*2 B
    unsigned short* abf  = ewt + (size_t)NFP_ * NFP_;             // 32768*896*2 B
    int*            gidx = (int*)(abf + (size_t)MTOT_ * KP_);     // 32768*4 B
    int*            cnt  = gidx + MTOT_;                          // 64*4 B

    setup_kernel<<<520, 512, 0, stream>>>(valid, gidx, cnt, seq, cls_w, cls_b, cls_out,
                                          b2, tag_out, enr_w, ewt, w1, w1t);
    pack_enrich<<<MTOT_ / 8 + MTOT_ / 32, 256, 0, stream>>>(seq, gidx, cnt, feat,
                                                            ewt, enr_b, abf);
    main_gemm<<<1536, 256, 0, stream>>>(abf, cnt, w1t, b1, w2, tag_out);
}